// Round 15
// baseline (403.611 us; speedup 1.0000x reference)
//
#include <hip/hip_runtime.h>
#include <hip/hip_fp16.h>

// ---------------------------------------------------------------------------
// MultiTaskGNN: 2-layer GAT (H=4 heads, C=32) + node head + edge MLP head.
// Adjacency: PADDED bucket build (64 slots/node, R13) - no hist, no scan:
//   init: cnt[i]=1, slot0 = self-loop. scatter: pos=atomicAdd(cnt[dv]),
//   esrc_pad[dv*64+pos]=src. Degrees ~Poisson(16): P(overflow) ~ 1e-19.
//   R14 NT-load experiment reverted (WRITE 80->64MB but dur flat: scatter is
//   atomic/write LATENCY-bound, not writeback-throughput-bound).
// R15: scatter fused with transform-L1 as UNIFORM DUAL-ROLE blocks: every
//   block of the same 1536-block grid does its scatter stripe, then
//   grid-strides MFMA transform tiles. Unlike R11's split-role fusion the
//   grid shape is identical to the standalone scatter, so the blockIdx&7 ==
//   XCD partition alignment is preserved; transform MFMA work fills
//   scatter's idle cycles (VALU 5%, BW 18%).
// Per layer:
//   transform: MFMA 16x16x32 f16, 16 nodes/tile, persistent waves.
//   aggregate: wave/node, 4 edge streams x 16 lanes, 16B half8 loads,
//              depth-2 pipeline unrolled x2. ~75us @ VALU 78% / 3.3TB/s -
//              near both the VALU and random-gather ceilings.
//   edge head: MFMA 16x16x32 f16, persistent waves (We1 frags loaded once).
// ---------------------------------------------------------------------------

#define NPART 8

using half8 = __attribute__((ext_vector_type(8))) _Float16;
using floatx4 = __attribute__((ext_vector_type(4))) float;

// cnt[i]=1 and self-loop in slot 0 of each node's padded row.
__global__ void init_pad_kernel(int* __restrict__ cnt, int* __restrict__ esrc_pad, int N) {
  int i = blockIdx.x * blockDim.x + threadIdx.x;
  if (i < N) {
    cnt[i] = 1;
    esrc_pad[(size_t)i << 6] = i;
  }
}

// Uniform dual-role kernel: (phase 1) partitioned padded scatter of this
// block's edge stripe; (phase 2) persistent-wave MFMA transform-L1 tiles.
__global__ __launch_bounds__(256) void scatter_transform_kernel(
    const int* __restrict__ src, const int* __restrict__ dst, int E,
    int* __restrict__ cnt, int* __restrict__ esrc_pad, int partSize,
    const float* __restrict__ xf, const float* __restrict__ W,
    const float* __restrict__ a_src, const float* __restrict__ a_dst,
    __half* __restrict__ h, float* __restrict__ s, float* __restrict__ d, int N) {
  // ---- phase 1: scatter (identical structure to the standalone R13 kernel)
  {
    int p = blockIdx.x & (NPART - 1);
    int sblk = blockIdx.x >> 3;
    int nsb = gridDim.x >> 3;
    int lo = p * partSize, hi = lo + partSize;
    int stride = nsb * blockDim.x;
    for (int i = sblk * blockDim.x + threadIdx.x; i < E; i += stride) {
      int dv = dst[i];
      if (dv >= lo && dv < hi) {
        int pos = atomicAdd(&cnt[dv], 1);
        if (pos < 64) esrc_pad[((size_t)dv << 6) + pos] = src[i];
      }
    }
  }
  // ---- phase 2: transform-L1 (fp32 x [N,9] input, Keff=9) ----
  int lane = threadIdx.x & 63;
  int quad = lane >> 4;
  int col = lane & 15;
  half8 af[8];
#pragma unroll
  for (int ct = 0; ct < 8; ++ct) {
#pragma unroll
    for (int j = 0; j < 8; ++j) {
      int k = quad * 8 + j;
      af[ct][j] = (k < 9) ? (_Float16)W[k * 128 + ct * 16 + col] : (_Float16)0.f;
    }
  }
  int ntile = (N + 15) >> 4;
  int wstep = gridDim.x * 4;
  for (int tile = blockIdx.x * 4 + (threadIdx.x >> 6); tile < ntile; tile += wstep) {
    int node = tile * 16 + col;
    int nclamp = min(node, N - 1);
    half8 bfr;
    const float* xr = xf + (size_t)nclamp * 9;
#pragma unroll
    for (int j = 0; j < 8; ++j) {
      int k = quad * 8 + j;
      bfr[j] = (k < 9) ? (_Float16)xr[k] : (_Float16)0.f;
    }
    floatx4 acc[8];
#pragma unroll
    for (int ct = 0; ct < 8; ++ct) acc[ct] = (floatx4){0.f, 0.f, 0.f, 0.f};
#pragma unroll
    for (int ct = 0; ct < 8; ++ct)
      acc[ct] = __builtin_amdgcn_mfma_f32_16x16x32_f16(af[ct], bfr, acc[ct], 0, 0, 0);
    float sp[4] = {0.f, 0.f, 0.f, 0.f}, dp[4] = {0.f, 0.f, 0.f, 0.f};
    bool wr = (node < N);
#pragma unroll
    for (int ct = 0; ct < 8; ++ct) {
      int f0 = ct * 16 + quad * 4;
      if (wr) {
        __half2 p0 = __floats2half2_rn(acc[ct][0], acc[ct][1]);
        __half2 p1 = __floats2half2_rn(acc[ct][2], acc[ct][3]);
        __half2* hp = (__half2*)(h + (size_t)node * 128 + f0);
        hp[0] = p0;
        hp[1] = p1;
      }
      int hh = ct >> 1;
      const float4 av = *(const float4*)(a_src + f0);
      const float4 dv = *(const float4*)(a_dst + f0);
      sp[hh] += acc[ct][0] * av.x + acc[ct][1] * av.y + acc[ct][2] * av.z + acc[ct][3] * av.w;
      dp[hh] += acc[ct][0] * dv.x + acc[ct][1] * dv.y + acc[ct][2] * dv.z + acc[ct][3] * dv.w;
    }
#pragma unroll
    for (int hh = 0; hh < 4; ++hh) {
      sp[hh] += __shfl_xor(sp[hh], 16);
      sp[hh] += __shfl_xor(sp[hh], 32);
      dp[hh] += __shfl_xor(dp[hh], 16);
      dp[hh] += __shfl_xor(dp[hh], 32);
    }
    if (quad == 0 && wr) {
      *(float4*)(s + node * 4) = make_float4(sp[0], sp[1], sp[2], sp[3]);
      *(float4*)(d + node * 4) = make_float4(dp[0], dp[1], dp[2], dp[3]);
    }
  }
}

// Layer-2 MFMA transform: persistent waves, fp16 input rows (16B B-frag load).
__global__ __launch_bounds__(256) void transform_mfma_kernel(
    const __half* __restrict__ xh, const float* __restrict__ W,
    const float* __restrict__ a_src, const float* __restrict__ a_dst,
    __half* __restrict__ h, float* __restrict__ s, float* __restrict__ d, int N) {
  int lane = threadIdx.x & 63;
  int quad = lane >> 4;
  int col = lane & 15;
  half8 af[8];
#pragma unroll
  for (int ct = 0; ct < 8; ++ct) {
#pragma unroll
    for (int j = 0; j < 8; ++j) {
      int k = quad * 8 + j;
      af[ct][j] = (_Float16)W[k * 128 + ct * 16 + col];
    }
  }
  int ntile = (N + 15) >> 4;
  int wstep = gridDim.x * 4;
  for (int tile = blockIdx.x * 4 + (threadIdx.x >> 6); tile < ntile; tile += wstep) {
    int node = tile * 16 + col;
    int nclamp = min(node, N - 1);
    half8 bfr = *(const half8*)(xh + (size_t)nclamp * 32 + quad * 8);
    floatx4 acc[8];
#pragma unroll
    for (int ct = 0; ct < 8; ++ct) acc[ct] = (floatx4){0.f, 0.f, 0.f, 0.f};
#pragma unroll
    for (int ct = 0; ct < 8; ++ct)
      acc[ct] = __builtin_amdgcn_mfma_f32_16x16x32_f16(af[ct], bfr, acc[ct], 0, 0, 0);
    float sp[4] = {0.f, 0.f, 0.f, 0.f}, dp[4] = {0.f, 0.f, 0.f, 0.f};
    bool wr = (node < N);
#pragma unroll
    for (int ct = 0; ct < 8; ++ct) {
      int f0 = ct * 16 + quad * 4;
      if (wr) {
        __half2 p0 = __floats2half2_rn(acc[ct][0], acc[ct][1]);
        __half2 p1 = __floats2half2_rn(acc[ct][2], acc[ct][3]);
        __half2* hp = (__half2*)(h + (size_t)node * 128 + f0);
        hp[0] = p0;
        hp[1] = p1;
      }
      int hh = ct >> 1;
      const float4 av = *(const float4*)(a_src + f0);
      const float4 dv = *(const float4*)(a_dst + f0);
      sp[hh] += acc[ct][0] * av.x + acc[ct][1] * av.y + acc[ct][2] * av.z + acc[ct][3] * av.w;
      dp[hh] += acc[ct][0] * dv.x + acc[ct][1] * dv.y + acc[ct][2] * dv.z + acc[ct][3] * dv.w;
    }
#pragma unroll
    for (int hh = 0; hh < 4; ++hh) {
      sp[hh] += __shfl_xor(sp[hh], 16);
      sp[hh] += __shfl_xor(sp[hh], 32);
      dp[hh] += __shfl_xor(dp[hh], 16);
      dp[hh] += __shfl_xor(dp[hh], 32);
    }
    if (quad == 0 && wr) {
      *(float4*)(s + node * 4) = make_float4(sp[0], sp[1], sp[2], sp[3]);
      *(float4*)(d + node * 4) = make_float4(dp[0], dp[1], dp[2], dp[3]);
    }
  }
}

// One wave per dst node. 4 edge streams (g = lane>>4), 16 lanes/edge;
// lane k (0..15) covers flat channels 8k..8k+7 (one 16B half8 load),
// head = k>>2. Depth-2 pipeline UNROLLED x2 (zero rotation moves).
// Adjacency from the padded rows: beg = wid*64, cnt from cntArr.
// out16: next-layer fp16 input. Wn != nullptr: fused node head.
__global__ void aggregate_kernel(const __half* __restrict__ h, const float* __restrict__ s,
                                 const float* __restrict__ d, const int* __restrict__ cntArr,
                                 const int* __restrict__ esrc, const float* __restrict__ bias,
                                 float* __restrict__ out, __half* __restrict__ out16,
                                 const float* __restrict__ Wn, const float* __restrict__ bn,
                                 float* __restrict__ out_node, int N) {
  int wid = blockIdx.x * (blockDim.x >> 6) + (threadIdx.x >> 6);
  if (wid >= N) return;
  int lane = threadIdx.x & 63;
  int g = lane >> 4;   // edge stream 0..3
  int k = lane & 15;   // channel block: flat channels 8k..8k+7
  int head = k >> 2;
  float dsel = d[wid * 4 + head];
  int beg = wid << 6;
  int cnt = min(cntArr[wid], 64);  // >= 1 (self-loop in slot 0)
  int end = beg + cnt;
  int M = (cnt + 3) >> 2;          // steps for the longest stream
  int i0 = beg + g;
  int last = end - 1;
  const half8* hrow = (const half8*)h;  // node row = 16 half8 blocks

  float acc[8] = {0.f, 0.f, 0.f, 0.f, 0.f, 0.f, 0.f, 0.f};
  float den = 0.f;

  // prologue: steps 0,1 data + steps 2,3 srcs
  int srcA = esrc[min(i0, last)];
  int srcB = esrc[min(i0 + 4, last)];
  float sv0 = s[srcA * 4 + head];
  half8 hv0 = hrow[(size_t)srcA * 16 + k];
  float sv1 = s[srcB * 4 + head];
  half8 hv1 = hrow[(size_t)srcB * 16 + k];
  srcA = esrc[min(i0 + 8, last)];
  srcB = esrc[min(i0 + 12, last)];

  int Mp = (M + 1) >> 1;  // pairs (odd tail masked by e=0 + clamped loads)
  for (int p = 0; p < Mp; ++p) {
    int t = 2 * p;
    // ---- step t: compute on (sv0,hv0), then refill them for step t+2 ----
    {
      float a = sv0 + dsel;
      a = fmaxf(a, 0.2f * a);
      float e = __expf(a);
      e = (i0 + 4 * t < end) ? e : 0.f;
      den += e;
      const __half2* hp = (const __half2*)&hv0;
#pragma unroll
      for (int q = 0; q < 4; ++q) {
        float2 f = __half22float2(hp[q]);
        acc[2 * q] = fmaf(e, f.x, acc[2 * q]);
        acc[2 * q + 1] = fmaf(e, f.y, acc[2 * q + 1]);
      }
    }
    sv0 = s[srcA * 4 + head];
    hv0 = hrow[(size_t)srcA * 16 + k];
    srcA = esrc[min(i0 + 4 * (t + 4), last)];
    // ---- step t+1: compute on (sv1,hv1), refill for step t+3 ----
    {
      float a = sv1 + dsel;
      a = fmaxf(a, 0.2f * a);
      float e = __expf(a);
      e = (i0 + 4 * (t + 1) < end) ? e : 0.f;
      den += e;
      const __half2* hp = (const __half2*)&hv1;
#pragma unroll
      for (int q = 0; q < 4; ++q) {
        float2 f = __half22float2(hp[q]);
        acc[2 * q] = fmaf(e, f.x, acc[2 * q]);
        acc[2 * q + 1] = fmaf(e, f.y, acc[2 * q + 1]);
      }
    }
    sv1 = s[srcB * 4 + head];
    hv1 = hrow[(size_t)srcB * 16 + k];
    srcB = esrc[min(i0 + 4 * (t + 5), last)];
  }

  // merge the 4 edge streams (xor 16, 32), then softmax divide
  den += __shfl_xor(den, 16);
  den += __shfl_xor(den, 32);
#pragma unroll
  for (int q = 0; q < 8; ++q) {
    acc[q] += __shfl_xor(acc[q], 16);
    acc[q] += __shfl_xor(acc[q], 32);
  }
  float inv = 1.f / den;
  // mean over heads: same channel block lives at k, k^4, k^8, k^12
#pragma unroll
  for (int q = 0; q < 8; ++q) {
    acc[q] *= inv;
    acc[q] += __shfl_xor(acc[q], 4);
    acc[q] += __shfl_xor(acc[q], 8);
  }
  if (lane < 4) {  // g==0, k=0..3: output channels 8k..8k+7
#pragma unroll
    for (int q = 0; q < 8; ++q)
      acc[q] = fmaxf(acc[q] * 0.25f + bias[8 * k + q], 0.f);
    if (out) {
      float4 o0 = make_float4(acc[0], acc[1], acc[2], acc[3]);
      float4 o1 = make_float4(acc[4], acc[5], acc[6], acc[7]);
      ((float4*)out)[(size_t)wid * 8 + 2 * k] = o0;
      ((float4*)out)[(size_t)wid * 8 + 2 * k + 1] = o1;
    }
    if (out16) {  // fp16 output (next-layer MFMA input / edge head)
      half8 hv;
#pragma unroll
      for (int q = 0; q < 8; ++q) hv[q] = (_Float16)acc[q];
      ((half8*)out16)[(size_t)wid * 4 + k] = hv;
    }
    if (Wn) {  // fused node head (layer 2 only)
      float p0 = 0.f, p1 = 0.f;
#pragma unroll
      for (int q = 0; q < 8; ++q) {
        int c = 8 * k + q;
        p0 = fmaf(acc[q], Wn[c * 2], p0);
        p1 = fmaf(acc[q], Wn[c * 2 + 1], p1);
      }
      p0 += __shfl_xor(p0, 1); p1 += __shfl_xor(p1, 1);
      p0 += __shfl_xor(p0, 2); p1 += __shfl_xor(p1, 2);
      if (k == 0) {
        out_node[wid * 2] = p0 + bn[0];
        out_node[wid * 2 + 1] = p1 + bn[1];
      }
    }
  }
}

// MFMA edge head, persistent waves. M=16 edges/group, N=64 hidden, K=64.
// B-frags (We1) loaded ONCE per wave, then grid-stride over edge groups.
__global__ __launch_bounds__(256) void edge_head_mfma_kernel(
    const __half* __restrict__ h2, const int* __restrict__ eli, int EL,
    const float* __restrict__ We1, const float* __restrict__ be1,
    const float* __restrict__ We2, const float* __restrict__ be2, float* __restrict__ out) {
  int lane = threadIdx.x & 63;
  int quad = lane >> 4;
  int col = lane & 15;

  half8 bf[2][4];
#pragma unroll
  for (int ks = 0; ks < 2; ++ks)
#pragma unroll
    for (int nt = 0; nt < 4; ++nt)
#pragma unroll
      for (int i = 0; i < 8; ++i)
        bf[ks][nt][i] = (_Float16)We1[(ks * 32 + quad * 8 + i) * 64 + nt * 16 + col];

  float b1v[4], w2v[4];
#pragma unroll
  for (int nt = 0; nt < 4; ++nt) {
    b1v[nt] = be1[nt * 16 + col];
    w2v[nt] = We2[nt * 16 + col];
  }
  float be2v = be2[0];

  int ngroups = (EL + 15) >> 4;
  int wstep = gridDim.x * 4;
  for (int group = blockIdx.x * 4 + (threadIdx.x >> 6); group < ngroups; group += wstep) {
    int e = min(group * 16 + col, EL - 1);
    int a = eli[e];
    int b = eli[EL + e];
    half8 af0 = *(const half8*)(h2 + (size_t)a * 32 + quad * 8);
    half8 af1 = *(const half8*)(h2 + (size_t)b * 32 + quad * 8);

    floatx4 acc[4];
#pragma unroll
    for (int nt = 0; nt < 4; ++nt) acc[nt] = (floatx4){0.f, 0.f, 0.f, 0.f};
#pragma unroll
    for (int nt = 0; nt < 4; ++nt)
      acc[nt] = __builtin_amdgcn_mfma_f32_16x16x32_f16(af0, bf[0][nt], acc[nt], 0, 0, 0);
#pragma unroll
    for (int nt = 0; nt < 4; ++nt)
      acc[nt] = __builtin_amdgcn_mfma_f32_16x16x32_f16(af1, bf[1][nt], acc[nt], 0, 0, 0);

#pragma unroll
    for (int reg = 0; reg < 4; ++reg) {
      float p = 0.f;
#pragma unroll
      for (int nt = 0; nt < 4; ++nt) {
        float z = acc[nt][reg] + b1v[nt];
        z = fmaxf(z, 0.f);
        p = fmaf(z, w2v[nt], p);
      }
      p += __shfl_xor(p, 1);
      p += __shfl_xor(p, 2);
      p += __shfl_xor(p, 4);
      p += __shfl_xor(p, 8);
      if (col == 0) {
        int eo = group * 16 + quad * 4 + reg;
        if (eo < EL) out[eo] = p + be2v;
      }
    }
  }
}

extern "C" void kernel_launch(void* const* d_in, const int* in_sizes, int n_in,
                              void* d_out, int out_size, void* d_ws, size_t ws_size,
                              hipStream_t stream) {
  const float* x = (const float*)d_in[0];
  const int* ei = (const int*)d_in[1];
  const int* eli = (const int*)d_in[2];
  const float* W1 = (const float*)d_in[3];
  const float* a_src1 = (const float*)d_in[4];
  const float* a_dst1 = (const float*)d_in[5];
  const float* b1 = (const float*)d_in[6];
  const float* W2 = (const float*)d_in[7];
  const float* a_src2 = (const float*)d_in[8];
  const float* a_dst2 = (const float*)d_in[9];
  const float* b2 = (const float*)d_in[10];
  const float* Wn = (const float*)d_in[11];
  const float* bn = (const float*)d_in[12];
  const float* We1 = (const float*)d_in[13];
  const float* be1 = (const float*)d_in[14];
  const float* We2 = (const float*)d_in[15];
  const float* be2 = (const float*)d_in[16];

  const int N = in_sizes[0] / 9;   // DIN = 9
  const int E = in_sizes[1] / 2;
  const int EL = in_sizes[2] / 2;

  // workspace layout (float units)
  float* wsf = (float*)d_ws;
  __half* h_half = (__half*)wsf;                    // N*128 halves  [0, 64N)
  float* sbuf = wsf + (size_t)N * 64;               // N*4           [64N, 68N)
  float* dbuf = sbuf + (size_t)N * 4;               // N*4           [68N, 72N)
  __half* h1h = (__half*)(wsf + (size_t)N * 72);    // N*32 halves   [72N, 88N)
  __half* h2h = (__half*)(wsf + (size_t)N * 88);    // N*32 halves   [88N, 104N)
  int* cnt = (int*)(wsf + (size_t)N * 104);         // N             [104N, 105N)
  int* esrc_pad = cnt + N;                          // N*64          [105N, 169N)

  float* out_node = (float*)d_out;            // N*2
  float* out_edge = out_node + (size_t)N * 2; // EL

  const int B = 256;
  const int wavesPerBlock = B / 64;
  int gridNwave = (N + wavesPerBlock - 1) / wavesPerBlock;
  int partSize = (N + NPART - 1) / NPART;
  int gridPart = NPART * 192;  // 8 partitions x 192 edge stripes

  // --- padded adjacency build (self-loop in slot 0; no hist/scan needed) ---
  init_pad_kernel<<<(N + B - 1) / B, B, 0, stream>>>(cnt, esrc_pad, N);

  // --- scatter + layer-1 transform, uniform dual-role blocks ---
  scatter_transform_kernel<<<gridPart, B, 0, stream>>>(
      ei, ei + E, E, cnt, esrc_pad, partSize,
      x, W1, a_src1, a_dst1, h_half, sbuf, dbuf, N);
  aggregate_kernel<<<gridNwave, B, 0, stream>>>(h_half, sbuf, dbuf, cnt, esrc_pad, b1,
                                                nullptr, h1h, nullptr, nullptr, nullptr, N);

  // --- layer 2 (node head fused; h2 emitted fp16) ---
  transform_mfma_kernel<<<512, B, 0, stream>>>(h1h, W2, a_src2, a_dst2,
                                               h_half, sbuf, dbuf, N);
  aggregate_kernel<<<gridNwave, B, 0, stream>>>(h_half, sbuf, dbuf, cnt, esrc_pad, b2,
                                                nullptr, h2h, Wn, bn, out_node, N);

  // --- edge head (MFMA, persistent waves) ---
  edge_head_mfma_kernel<<<1024, B, 0, stream>>>(h2h, eli, EL, We1, be1, We2, be2, out_edge);
}

// Round 16
// 375.827 us; speedup vs baseline: 1.0739x; 1.0739x over previous
//
#include <hip/hip_runtime.h>
#include <hip/hip_fp16.h>

// ---------------------------------------------------------------------------
// MultiTaskGNN: 2-layer GAT (H=4 heads, C=32) + node head + edge MLP head.
// Adjacency: PADDED bucket build (64 slots/node, R13) - no hist, no scan:
//   init: cnt[i]=1, slot0 = self-loop. scatter: pos=atomicAdd(cnt[dv]),
//   esrc_pad[dv*64+pos]=src. Degrees ~Poisson(16): P(overflow) ~ 1e-19.
//   R16: scatter unrolled x4 (batched independent loads + atomic chains)
//   for memory-level parallelism - scatter is atomic-LATENCY bound
//   (VALU 5%, BW 18%; R14 NT-loads cut WRITE but not time).
// FUSION LESSONS (R11, R15 - both failed): never fuse a low-VGPR
//   latency-bound phase (scatter, 8 VGPR, needs max occupancy) into a
//   high-VGPR MFMA kernel (88 VGPR -> 22% occupancy) - occupancy is set by
//   the max, and the stretched scatter re-breaks L2 write accumulation
//   (WRITE 80 -> 107MB). Role-pure uniform grids only.
// Per layer:
//   transform: MFMA 16x16x32 f16, 16 nodes/tile, persistent waves.
//   aggregate: wave/node, 4 edge streams x 16 lanes, 16B half8 loads,
//              depth-2 pipeline unrolled x2. ~75us @ VALU 78% / 3.3TB/s -
//              near both the VALU and random-gather ceilings.
//   edge head: MFMA 16x16x32 f16, persistent waves (We1 frags loaded once).
// ---------------------------------------------------------------------------

#define NPART 8

using half8 = __attribute__((ext_vector_type(8))) _Float16;
using floatx4 = __attribute__((ext_vector_type(4))) float;

// cnt[i]=1 and self-loop in slot 0 of each node's padded row.
__global__ void init_pad_kernel(int* __restrict__ cnt, int* __restrict__ esrc_pad, int N) {
  int i = blockIdx.x * blockDim.x + threadIdx.x;
  if (i < N) {
    cnt[i] = 1;
    esrc_pad[(size_t)i << 6] = i;
  }
}

// Partitioned padded scatter, unrolled x4: 4 independent dst loads batch
// ahead, then 4 independent predicated atomic+store chains overlap their
// round-trip latencies (R16: single-chain version was latency-serialized
// at ~82us with VALU 5%).
__global__ void scatter_pad_kernel(const int* __restrict__ src, const int* __restrict__ dst,
                                   int E, int* __restrict__ cnt, int* __restrict__ esrc_pad,
                                   int partSize) {
  int p = blockIdx.x & (NPART - 1);
  int sblk = blockIdx.x >> 3;
  int nsb = gridDim.x >> 3;
  int lo = p * partSize, hi = lo + partSize;
  int step = nsb * blockDim.x;
  int base = sblk * blockDim.x + threadIdx.x;
  int i = base;
  // main unrolled body
  for (; i + 3 * step < E; i += 4 * step) {
    int i1 = i + step, i2 = i + 2 * step, i3 = i + 3 * step;
    int d0 = dst[i];
    int d1 = dst[i1];
    int d2 = dst[i2];
    int d3 = dst[i3];
    bool m0 = (d0 >= lo && d0 < hi);
    bool m1 = (d1 >= lo && d1 < hi);
    bool m2 = (d2 >= lo && d2 < hi);
    bool m3 = (d3 >= lo && d3 < hi);
    if (m0) {
      int pos = atomicAdd(&cnt[d0], 1);
      if (pos < 64) esrc_pad[((size_t)d0 << 6) + pos] = src[i];
    }
    if (m1) {
      int pos = atomicAdd(&cnt[d1], 1);
      if (pos < 64) esrc_pad[((size_t)d1 << 6) + pos] = src[i1];
    }
    if (m2) {
      int pos = atomicAdd(&cnt[d2], 1);
      if (pos < 64) esrc_pad[((size_t)d2 << 6) + pos] = src[i2];
    }
    if (m3) {
      int pos = atomicAdd(&cnt[d3], 1);
      if (pos < 64) esrc_pad[((size_t)d3 << 6) + pos] = src[i3];
    }
  }
  // tail
  for (; i < E; i += step) {
    int dv = dst[i];
    if (dv >= lo && dv < hi) {
      int pos = atomicAdd(&cnt[dv], 1);
      if (pos < 64) esrc_pad[((size_t)dv << 6) + pos] = src[i];
    }
  }
}

// MFMA transform: persistent waves over 16-node tiles. L1=true: fp32 x [N,9]
// input, B-frag by direct converts (k>=9 -> 0). Else fp16 rows, 16B load.
// D' = W^T x^T via mfma_f32_16x16x32_f16 (layouts verified R7/R9).
template <bool L1>
__global__ __launch_bounds__(256) void transform_mfma_kernel(
    const float* __restrict__ xf, const __half* __restrict__ xh,
    const float* __restrict__ W, int Keff,
    const float* __restrict__ a_src, const float* __restrict__ a_dst,
    __half* __restrict__ h, float* __restrict__ s, float* __restrict__ d, int N) {
  int lane = threadIdx.x & 63;
  int quad = lane >> 4;
  int col = lane & 15;

  // A-frags: W^T tiles, fp32->fp16, zero for k >= Keff. Loaded once per wave.
  half8 af[8];
#pragma unroll
  for (int ct = 0; ct < 8; ++ct) {
#pragma unroll
    for (int j = 0; j < 8; ++j) {
      int k = quad * 8 + j;
      af[ct][j] = (k < Keff) ? (_Float16)W[k * 128 + ct * 16 + col] : (_Float16)0.f;
    }
  }

  int ntile = (N + 15) >> 4;
  int wstep = gridDim.x * 4;
  for (int tile = blockIdx.x * 4 + (threadIdx.x >> 6); tile < ntile; tile += wstep) {
    int node = tile * 16 + col;
    int nclamp = min(node, N - 1);

    half8 bfr;
    if (L1) {
      const float* xr = xf + (size_t)nclamp * 9;
#pragma unroll
      for (int j = 0; j < 8; ++j) {
        int k = quad * 8 + j;
        bfr[j] = (k < 9) ? (_Float16)xr[k] : (_Float16)0.f;
      }
    } else {
      bfr = *(const half8*)(xh + (size_t)nclamp * 32 + quad * 8);
    }

    floatx4 acc[8];
#pragma unroll
    for (int ct = 0; ct < 8; ++ct) acc[ct] = (floatx4){0.f, 0.f, 0.f, 0.f};
#pragma unroll
    for (int ct = 0; ct < 8; ++ct)
      acc[ct] = __builtin_amdgcn_mfma_f32_16x16x32_f16(af[ct], bfr, acc[ct], 0, 0, 0);

    // epilogue: h stores + s/d head dots
    float sp[4] = {0.f, 0.f, 0.f, 0.f}, dp[4] = {0.f, 0.f, 0.f, 0.f};
    bool wr = (node < N);
#pragma unroll
    for (int ct = 0; ct < 8; ++ct) {
      int f0 = ct * 16 + quad * 4;
      if (wr) {
        __half2 p0 = __floats2half2_rn(acc[ct][0], acc[ct][1]);
        __half2 p1 = __floats2half2_rn(acc[ct][2], acc[ct][3]);
        __half2* hp = (__half2*)(h + (size_t)node * 128 + f0);
        hp[0] = p0;
        hp[1] = p1;
      }
      int hh = ct >> 1;
      const float4 av = *(const float4*)(a_src + f0);
      const float4 dv = *(const float4*)(a_dst + f0);
      sp[hh] += acc[ct][0] * av.x + acc[ct][1] * av.y + acc[ct][2] * av.z + acc[ct][3] * av.w;
      dp[hh] += acc[ct][0] * dv.x + acc[ct][1] * dv.y + acc[ct][2] * dv.z + acc[ct][3] * dv.w;
    }
#pragma unroll
    for (int hh = 0; hh < 4; ++hh) {
      sp[hh] += __shfl_xor(sp[hh], 16);
      sp[hh] += __shfl_xor(sp[hh], 32);
      dp[hh] += __shfl_xor(dp[hh], 16);
      dp[hh] += __shfl_xor(dp[hh], 32);
    }
    if (quad == 0 && wr) {
      *(float4*)(s + node * 4) = make_float4(sp[0], sp[1], sp[2], sp[3]);
      *(float4*)(d + node * 4) = make_float4(dp[0], dp[1], dp[2], dp[3]);
    }
  }
}

// One wave per dst node. 4 edge streams (g = lane>>4), 16 lanes/edge;
// lane k (0..15) covers flat channels 8k..8k+7 (one 16B half8 load),
// head = k>>2. Depth-2 pipeline UNROLLED x2 (zero rotation moves).
// Adjacency from the padded rows: beg = wid*64, cnt from cntArr.
// out16: next-layer fp16 input. Wn != nullptr: fused node head.
__global__ void aggregate_kernel(const __half* __restrict__ h, const float* __restrict__ s,
                                 const float* __restrict__ d, const int* __restrict__ cntArr,
                                 const int* __restrict__ esrc, const float* __restrict__ bias,
                                 float* __restrict__ out, __half* __restrict__ out16,
                                 const float* __restrict__ Wn, const float* __restrict__ bn,
                                 float* __restrict__ out_node, int N) {
  int wid = blockIdx.x * (blockDim.x >> 6) + (threadIdx.x >> 6);
  if (wid >= N) return;
  int lane = threadIdx.x & 63;
  int g = lane >> 4;   // edge stream 0..3
  int k = lane & 15;   // channel block: flat channels 8k..8k+7
  int head = k >> 2;
  float dsel = d[wid * 4 + head];
  int beg = wid << 6;
  int cnt = min(cntArr[wid], 64);  // >= 1 (self-loop in slot 0)
  int end = beg + cnt;
  int M = (cnt + 3) >> 2;          // steps for the longest stream
  int i0 = beg + g;
  int last = end - 1;
  const half8* hrow = (const half8*)h;  // node row = 16 half8 blocks

  float acc[8] = {0.f, 0.f, 0.f, 0.f, 0.f, 0.f, 0.f, 0.f};
  float den = 0.f;

  // prologue: steps 0,1 data + steps 2,3 srcs
  int srcA = esrc[min(i0, last)];
  int srcB = esrc[min(i0 + 4, last)];
  float sv0 = s[srcA * 4 + head];
  half8 hv0 = hrow[(size_t)srcA * 16 + k];
  float sv1 = s[srcB * 4 + head];
  half8 hv1 = hrow[(size_t)srcB * 16 + k];
  srcA = esrc[min(i0 + 8, last)];
  srcB = esrc[min(i0 + 12, last)];

  int Mp = (M + 1) >> 1;  // pairs (odd tail masked by e=0 + clamped loads)
  for (int p = 0; p < Mp; ++p) {
    int t = 2 * p;
    // ---- step t: compute on (sv0,hv0), then refill them for step t+2 ----
    {
      float a = sv0 + dsel;
      a = fmaxf(a, 0.2f * a);
      float e = __expf(a);
      e = (i0 + 4 * t < end) ? e : 0.f;
      den += e;
      const __half2* hp = (const __half2*)&hv0;
#pragma unroll
      for (int q = 0; q < 4; ++q) {
        float2 f = __half22float2(hp[q]);
        acc[2 * q] = fmaf(e, f.x, acc[2 * q]);
        acc[2 * q + 1] = fmaf(e, f.y, acc[2 * q + 1]);
      }
    }
    sv0 = s[srcA * 4 + head];
    hv0 = hrow[(size_t)srcA * 16 + k];
    srcA = esrc[min(i0 + 4 * (t + 4), last)];
    // ---- step t+1: compute on (sv1,hv1), refill for step t+3 ----
    {
      float a = sv1 + dsel;
      a = fmaxf(a, 0.2f * a);
      float e = __expf(a);
      e = (i0 + 4 * (t + 1) < end) ? e : 0.f;
      den += e;
      const __half2* hp = (const __half2*)&hv1;
#pragma unroll
      for (int q = 0; q < 4; ++q) {
        float2 f = __half22float2(hp[q]);
        acc[2 * q] = fmaf(e, f.x, acc[2 * q]);
        acc[2 * q + 1] = fmaf(e, f.y, acc[2 * q + 1]);
      }
    }
    sv1 = s[srcB * 4 + head];
    hv1 = hrow[(size_t)srcB * 16 + k];
    srcB = esrc[min(i0 + 4 * (t + 5), last)];
  }

  // merge the 4 edge streams (xor 16, 32), then softmax divide
  den += __shfl_xor(den, 16);
  den += __shfl_xor(den, 32);
#pragma unroll
  for (int q = 0; q < 8; ++q) {
    acc[q] += __shfl_xor(acc[q], 16);
    acc[q] += __shfl_xor(acc[q], 32);
  }
  float inv = 1.f / den;
  // mean over heads: same channel block lives at k, k^4, k^8, k^12
#pragma unroll
  for (int q = 0; q < 8; ++q) {
    acc[q] *= inv;
    acc[q] += __shfl_xor(acc[q], 4);
    acc[q] += __shfl_xor(acc[q], 8);
  }
  if (lane < 4) {  // g==0, k=0..3: output channels 8k..8k+7
#pragma unroll
    for (int q = 0; q < 8; ++q)
      acc[q] = fmaxf(acc[q] * 0.25f + bias[8 * k + q], 0.f);
    if (out) {
      float4 o0 = make_float4(acc[0], acc[1], acc[2], acc[3]);
      float4 o1 = make_float4(acc[4], acc[5], acc[6], acc[7]);
      ((float4*)out)[(size_t)wid * 8 + 2 * k] = o0;
      ((float4*)out)[(size_t)wid * 8 + 2 * k + 1] = o1;
    }
    if (out16) {  // fp16 output (next-layer MFMA input / edge head)
      half8 hv;
#pragma unroll
      for (int q = 0; q < 8; ++q) hv[q] = (_Float16)acc[q];
      ((half8*)out16)[(size_t)wid * 4 + k] = hv;
    }
    if (Wn) {  // fused node head (layer 2 only)
      float p0 = 0.f, p1 = 0.f;
#pragma unroll
      for (int q = 0; q < 8; ++q) {
        int c = 8 * k + q;
        p0 = fmaf(acc[q], Wn[c * 2], p0);
        p1 = fmaf(acc[q], Wn[c * 2 + 1], p1);
      }
      p0 += __shfl_xor(p0, 1); p1 += __shfl_xor(p1, 1);
      p0 += __shfl_xor(p0, 2); p1 += __shfl_xor(p1, 2);
      if (k == 0) {
        out_node[wid * 2] = p0 + bn[0];
        out_node[wid * 2 + 1] = p1 + bn[1];
      }
    }
  }
}

// MFMA edge head, persistent waves. M=16 edges/group, N=64 hidden, K=64.
// B-frags (We1) loaded ONCE per wave, then grid-stride over edge groups.
__global__ __launch_bounds__(256) void edge_head_mfma_kernel(
    const __half* __restrict__ h2, const int* __restrict__ eli, int EL,
    const float* __restrict__ We1, const float* __restrict__ be1,
    const float* __restrict__ We2, const float* __restrict__ be2, float* __restrict__ out) {
  int lane = threadIdx.x & 63;
  int quad = lane >> 4;
  int col = lane & 15;

  half8 bf[2][4];
#pragma unroll
  for (int ks = 0; ks < 2; ++ks)
#pragma unroll
    for (int nt = 0; nt < 4; ++nt)
#pragma unroll
      for (int i = 0; i < 8; ++i)
        bf[ks][nt][i] = (_Float16)We1[(ks * 32 + quad * 8 + i) * 64 + nt * 16 + col];

  float b1v[4], w2v[4];
#pragma unroll
  for (int nt = 0; nt < 4; ++nt) {
    b1v[nt] = be1[nt * 16 + col];
    w2v[nt] = We2[nt * 16 + col];
  }
  float be2v = be2[0];

  int ngroups = (EL + 15) >> 4;
  int wstep = gridDim.x * 4;
  for (int group = blockIdx.x * 4 + (threadIdx.x >> 6); group < ngroups; group += wstep) {
    int e = min(group * 16 + col, EL - 1);
    int a = eli[e];
    int b = eli[EL + e];
    half8 af0 = *(const half8*)(h2 + (size_t)a * 32 + quad * 8);
    half8 af1 = *(const half8*)(h2 + (size_t)b * 32 + quad * 8);

    floatx4 acc[4];
#pragma unroll
    for (int nt = 0; nt < 4; ++nt) acc[nt] = (floatx4){0.f, 0.f, 0.f, 0.f};
#pragma unroll
    for (int nt = 0; nt < 4; ++nt)
      acc[nt] = __builtin_amdgcn_mfma_f32_16x16x32_f16(af0, bf[0][nt], acc[nt], 0, 0, 0);
#pragma unroll
    for (int nt = 0; nt < 4; ++nt)
      acc[nt] = __builtin_amdgcn_mfma_f32_16x16x32_f16(af1, bf[1][nt], acc[nt], 0, 0, 0);

#pragma unroll
    for (int reg = 0; reg < 4; ++reg) {
      float p = 0.f;
#pragma unroll
      for (int nt = 0; nt < 4; ++nt) {
        float z = acc[nt][reg] + b1v[nt];
        z = fmaxf(z, 0.f);
        p = fmaf(z, w2v[nt], p);
      }
      p += __shfl_xor(p, 1);
      p += __shfl_xor(p, 2);
      p += __shfl_xor(p, 4);
      p += __shfl_xor(p, 8);
      if (col == 0) {
        int eo = group * 16 + quad * 4 + reg;
        if (eo < EL) out[eo] = p + be2v;
      }
    }
  }
}

extern "C" void kernel_launch(void* const* d_in, const int* in_sizes, int n_in,
                              void* d_out, int out_size, void* d_ws, size_t ws_size,
                              hipStream_t stream) {
  const float* x = (const float*)d_in[0];
  const int* ei = (const int*)d_in[1];
  const int* eli = (const int*)d_in[2];
  const float* W1 = (const float*)d_in[3];
  const float* a_src1 = (const float*)d_in[4];
  const float* a_dst1 = (const float*)d_in[5];
  const float* b1 = (const float*)d_in[6];
  const float* W2 = (const float*)d_in[7];
  const float* a_src2 = (const float*)d_in[8];
  const float* a_dst2 = (const float*)d_in[9];
  const float* b2 = (const float*)d_in[10];
  const float* Wn = (const float*)d_in[11];
  const float* bn = (const float*)d_in[12];
  const float* We1 = (const float*)d_in[13];
  const float* be1 = (const float*)d_in[14];
  const float* We2 = (const float*)d_in[15];
  const float* be2 = (const float*)d_in[16];

  const int N = in_sizes[0] / 9;   // DIN = 9
  const int E = in_sizes[1] / 2;
  const int EL = in_sizes[2] / 2;

  // workspace layout (float units)
  float* wsf = (float*)d_ws;
  __half* h_half = (__half*)wsf;                    // N*128 halves  [0, 64N)
  float* sbuf = wsf + (size_t)N * 64;               // N*4           [64N, 68N)
  float* dbuf = sbuf + (size_t)N * 4;               // N*4           [68N, 72N)
  __half* h1h = (__half*)(wsf + (size_t)N * 72);    // N*32 halves   [72N, 88N)
  __half* h2h = (__half*)(wsf + (size_t)N * 88);    // N*32 halves   [88N, 104N)
  int* cnt = (int*)(wsf + (size_t)N * 104);         // N             [104N, 105N)
  int* esrc_pad = cnt + N;                          // N*64          [105N, 169N)

  float* out_node = (float*)d_out;            // N*2
  float* out_edge = out_node + (size_t)N * 2; // EL

  const int B = 256;
  const int wavesPerBlock = B / 64;
  int gridNwave = (N + wavesPerBlock - 1) / wavesPerBlock;
  int partSize = (N + NPART - 1) / NPART;
  int gridPart = NPART * 192;  // 8 partitions x 192 edge stripes

  // --- padded adjacency build (self-loop in slot 0; no hist/scan needed) ---
  init_pad_kernel<<<(N + B - 1) / B, B, 0, stream>>>(cnt, esrc_pad, N);
  scatter_pad_kernel<<<gridPart, B, 0, stream>>>(ei, ei + E, E, cnt, esrc_pad, partSize);

  // --- layer 1 (h1 emitted fp16) ---
  transform_mfma_kernel<true><<<512, B, 0, stream>>>(x, nullptr, W1, 9, a_src1, a_dst1,
                                                     h_half, sbuf, dbuf, N);
  aggregate_kernel<<<gridNwave, B, 0, stream>>>(h_half, sbuf, dbuf, cnt, esrc_pad, b1,
                                                nullptr, h1h, nullptr, nullptr, nullptr, N);

  // --- layer 2 (node head fused; h2 emitted fp16) ---
  transform_mfma_kernel<false><<<512, B, 0, stream>>>(nullptr, h1h, W2, 32, a_src2, a_dst2,
                                                      h_half, sbuf, dbuf, N);
  aggregate_kernel<<<gridNwave, B, 0, stream>>>(h_half, sbuf, dbuf, cnt, esrc_pad, b2,
                                                nullptr, h2h, Wn, bn, out_node, N);

  // --- edge head (MFMA, persistent waves) ---
  edge_head_mfma_kernel<<<1024, B, 0, stream>>>(h2h, eli, EL, We1, be1, We2, be2, out_edge);
}